// Round 1
// baseline (282.150 us; speedup 1.0000x reference)
//
#include <hip/hip_runtime.h>
#include <math.h>

// Problem constants (fixed shapes)
#define CDIM 8
#define CSZ  4096
#define NB   8
#define ND   1024
#define NT   4096

// d_out layout (flat f32, return order)
static constexpr size_t ZQ_OFF  = 0;
static constexpr size_t CL_OFF  = (size_t)NB * ND * NT;          // 33554432
static constexpr size_t CBL_OFF = CL_OFF + NB;                   // +8
static constexpr size_t IDX_OFF = CBL_OFF + NB;                  // +8
static constexpr size_t LAT_OFF = IDX_OFF + (size_t)NB * NT;     // +32768

// d_ws layout (f64 element indices)
static constexpr size_t WSI_WIN      = 0;                 // wT[i*16+o]: f64 in-proj weights, transposed
static constexpr size_t WSI_CBNA     = 16384;             // f64-normalized cb_a [4096][8]
static constexpr size_t WSI_CBNB     = 16384 + 32768;     // f64-normalized cb_b
static constexpr size_t WSI_PART_PRE = 16384 + 65536;     // per-block loss partials [512]
static constexpr size_t WS_NEED_BYTES = (WSI_PART_PRE + 512) * 8;

__global__ void vq_prep(const float* __restrict__ w_in_a, const float* __restrict__ w_in_b,
                        const float* __restrict__ cb_a,  const float* __restrict__ cb_b,
                        double* __restrict__ ws) {
    int id = blockIdx.x * 256 + threadIdx.x;
    if (id < 16384) {
        // transpose weights to [i][16] so each i is one contiguous 128B scalar load
        int i = id >> 4, o = id & 15;
        float w = (o < 8) ? w_in_a[o * ND + i] : w_in_b[(o - 8) * ND + i];
        ws[WSI_WIN + id] = (double)w;
    } else if (id < 16384 + 2 * CSZ) {
        int e = id - 16384;
        const float* src = (e < CSZ) ? (cb_a + (size_t)e * CDIM)
                                     : (cb_b + (size_t)(e - CSZ) * CDIM);
        double c[CDIM]; double n2 = 0.0;
#pragma unroll
        for (int k = 0; k < CDIM; ++k) { c[k] = (double)src[k]; n2 = fma(c[k], c[k], n2); }
        double den = fmax(sqrt(n2), 1e-12);
        double* dst = ws + WSI_CBNA + (size_t)e * CDIM;
#pragma unroll
        for (int k = 0; k < CDIM; ++k) dst[k] = c[k] / den;
    }
}

// 512 blocks x 256 threads; block = 64 frames (one b, 64 consecutive t), lane <-> t.
template<bool PRE>
__global__ void __launch_bounds__(256, 2)
vq_main(const float* __restrict__ z,
        const float* __restrict__ w_in_a, const float* __restrict__ b_in_a,
        const float* __restrict__ w_in_b, const float* __restrict__ b_in_b,
        const float* __restrict__ w_out_a, const float* __restrict__ b_out_a,
        const float* __restrict__ w_out_b, const float* __restrict__ b_out_b,
        const float* __restrict__ cb_a, const float* __restrict__ cb_b,
        float* __restrict__ out,
        const double* __restrict__ wT,
        const double* __restrict__ cbnA,
        const double* __restrict__ cbnB,
        double* __restrict__ part) {
    const int tid  = threadIdx.x;
    const int lane = tid & 63;
    const int wave = __builtin_amdgcn_readfirstlane(tid >> 6);  // SGPR -> uniform addressing
    const int blk  = blockIdx.x;
    const int b    = blk >> 6;                  // 64 blocks per batch entry
    const int t    = ((blk & 63) << 6) + lane;

    __shared__ double red[4][64][17];           // +1 pad: 2-way banks only
    __shared__ double sBest[2][4][64];
    __shared__ int    sIdx[2][4][64];

    // ---------- Phase 1: partial in-projection over this wave's channel quarter ----------
    double acc[16];
#pragma unroll
    for (int k = 0; k < 16; ++k) acc[k] = 0.0;

    const float* zp = z + ((size_t)b * ND) * NT + t;   // z[b, i, t] = zp[i*NT], coalesced in t
    const int i0 = wave * 256;
    if (PRE) {
#pragma unroll 4
        for (int ii = 0; ii < 256; ++ii) {
            const int i = i0 + ii;
            const double zd = (double)zp[(size_t)i * NT];
            const double* wr = wT + (size_t)i * 16;    // uniform -> s_load
#pragma unroll
            for (int k = 0; k < 16; ++k) acc[k] = fma(wr[k], zd, acc[k]);
        }
    } else {
#pragma unroll 2
        for (int ii = 0; ii < 256; ++ii) {
            const int i = i0 + ii;
            const double zd = (double)zp[(size_t)i * NT];
#pragma unroll
            for (int o = 0; o < 8; ++o) {
                acc[o]     = fma((double)w_in_a[o * ND + i], zd, acc[o]);
                acc[8 + o] = fma((double)w_in_b[o * ND + i], zd, acc[8 + o]);
            }
        }
    }
#pragma unroll
    for (int k = 0; k < 16; ++k) red[wave][lane][k] = acc[k];
    __syncthreads();

    double za[16];
#pragma unroll
    for (int k = 0; k < 16; ++k)
        za[k] = ((red[0][lane][k] + red[1][lane][k]) + red[2][lane][k]) + red[3][lane][k];
#pragma unroll
    for (int k = 0; k < 8; ++k) { za[k] += (double)b_in_a[k]; za[8 + k] += (double)b_in_b[k]; }

    // latent = concat(z_a, z_b) along channels, f32
    if (wave == 0) {
#pragma unroll
        for (int k = 0; k < 16; ++k)
            out[LAT_OFF + ((size_t)b * 16 + k) * NT + t] = (float)za[k];
    }

    // ---------- Phase 2: l2-normalize (f64) ----------
    double ea[8], eb[8];
    {
        double n2 = 0.0;
#pragma unroll
        for (int k = 0; k < 8; ++k) n2 = fma(za[k], za[k], n2);
        double inv = 1.0 / fmax(sqrt(n2), 1e-12);
#pragma unroll
        for (int k = 0; k < 8; ++k) ea[k] = za[k] * inv;
    }
    {
        double n2 = 0.0;
#pragma unroll
        for (int k = 0; k < 8; ++k) n2 = fma(za[8 + k], za[8 + k], n2);
        double inv = 1.0 / fmax(sqrt(n2), 1e-12);
#pragma unroll
        for (int k = 0; k < 8; ++k) eb[k] = za[8 + k] * inv;
    }

    // ---------- Phase 3: argmax(sim) over this wave's codebook quarter ----------
    // argmin dist == argmax enc_n . cb_n ; strict ">" keeps FIRST max = np argmin tie rule
    double bestA = -1e300, bestB = -1e300;
    int ibA = 0, ibB = 0;
    const int j0 = wave << 10;
    if (PRE) {
        const double* cA = cbnA + (size_t)j0 * CDIM;
        const double* cB = cbnB + (size_t)j0 * CDIM;
#pragma unroll 2
        for (int jj = 0; jj < 1024; ++jj) {
            const double* ra = cA + (size_t)jj * CDIM;  // uniform -> s_load_dwordx16
            const double* rb = cB + (size_t)jj * CDIM;
            double sA = 0.0, sB = 0.0;
#pragma unroll
            for (int k = 0; k < 8; ++k) { sA = fma(ea[k], ra[k], sA); sB = fma(eb[k], rb[k], sB); }
            if (sA > bestA) { bestA = sA; ibA = j0 + jj; }
            if (sB > bestB) { bestB = sB; ibB = j0 + jj; }
        }
    } else {
        for (int jj = 0; jj < 1024; ++jj) {
            const int j = j0 + jj;
            const float* ra = cb_a + (size_t)j * CDIM;
            const float* rb = cb_b + (size_t)j * CDIM;
            double na = 0.0, nb = 0.0, sA = 0.0, sB = 0.0;
#pragma unroll
            for (int k = 0; k < 8; ++k) {
                double av = (double)ra[k], bv = (double)rb[k];
                na = fma(av, av, na); nb = fma(bv, bv, nb);
                sA = fma(ea[k], av, sA); sB = fma(eb[k], bv, sB);
            }
            sA /= fmax(sqrt(na), 1e-12);
            sB /= fmax(sqrt(nb), 1e-12);
            if (sA > bestA) { bestA = sA; ibA = j; }
            if (sB > bestB) { bestB = sB; ibB = j; }
        }
    }

    sBest[0][wave][lane] = bestA; sIdx[0][wave][lane] = ibA;
    sBest[1][wave][lane] = bestB; sIdx[1][wave][lane] = ibB;
    __syncthreads();

    // combine quarters ascending (ties -> lowest j, matching first-occurrence argmin)
    double bA = sBest[0][0][lane]; int iA = sIdx[0][0][lane];
    double bB = sBest[1][0][lane]; int iB = sIdx[1][0][lane];
#pragma unroll
    for (int w2 = 1; w2 < 4; ++w2) {
        double d = sBest[0][w2][lane]; int j2 = sIdx[0][w2][lane];
        if (d > bA) { bA = d; iA = j2; }
        d = sBest[1][w2][lane]; j2 = sIdx[1][w2][lane];
        if (d > bB) { bB = d; iB = j2; }
    }

    // gather RAW (unnormalized) codewords
    float4 qa0 = *(const float4*)(cb_a + (size_t)iA * CDIM);
    float4 qa1 = *(const float4*)(cb_a + (size_t)iA * CDIM + 4);
    float4 qb0 = *(const float4*)(cb_b + (size_t)iB * CDIM);
    float4 qb1 = *(const float4*)(cb_b + (size_t)iB * CDIM + 4);
    float zaq[8] = {qa0.x, qa0.y, qa0.z, qa0.w, qa1.x, qa1.y, qa1.z, qa1.w};
    float zbq[8] = {qb0.x, qb0.y, qb0.z, qb0.w, qb1.x, qb1.y, qb1.z, qb1.w};

    if (wave == 0) {
        // indices = idx_a*4096 + idx_b (< 2^24, exact in f32)
        out[IDX_OFF + (size_t)b * NT + t] = (float)(iA * CSZ + iB);
        // per-frame loss contribution (commitment == codebook loss in forward)
        double s = 0.0;
#pragma unroll
        for (int k = 0; k < 8; ++k) {
            double d0 = za[k]     - (double)zaq[k]; s = fma(d0, d0, s);
            double d1 = za[8 + k] - (double)zbq[k]; s = fma(d1, d1, s);
        }
#pragma unroll
        for (int off = 32; off > 0; off >>= 1) s += __shfl_down(s, off);
        if (lane == 0) part[blk] = s;
    }

    // ---------- Phase 4: output projection (f32), 128 channels per half per wave ----------
    const int c0 = wave << 7;
    const size_t obase = ((size_t)b * ND) * NT + t;
    for (int cc = 0; cc < 128; ++cc) {
        const int c = c0 + cc;
        const float* wa = w_out_a + (size_t)c * CDIM;  // uniform -> s_load
        const float* wb = w_out_b + (size_t)c * CDIM;
        float sa = b_out_a[c], sb = b_out_b[c];
#pragma unroll
        for (int k = 0; k < 8; ++k) { sa = fmaf(wa[k], zaq[k], sa); sb = fmaf(wb[k], zbq[k], sb); }
        out[obase + (size_t)c * NT]         = sa;       // out_a rows 0..511
        out[obase + (size_t)(512 + c) * NT] = sb;       // out_b rows 512..1023
    }
}

__global__ void vq_finalize(const double* __restrict__ part, float* __restrict__ out) {
    const int b = threadIdx.x;
    if (b < NB) {
        double s = 0.0;
        for (int j = 0; j < 64; ++j) s += part[(size_t)b * 64 + j];  // fixed order: deterministic
        const float v = (float)(s * (1.0 / 32768.0));  // mean over (8 x 4096), exact pow2 scale
        out[CL_OFF + b]  = v;
        out[CBL_OFF + b] = v;
    }
}

extern "C" void kernel_launch(void* const* d_in, const int* in_sizes, int n_in,
                              void* d_out, int out_size, void* d_ws, size_t ws_size,
                              hipStream_t stream) {
    const float* z       = (const float*)d_in[0];
    const float* w_in_a  = (const float*)d_in[1];
    const float* b_in_a  = (const float*)d_in[2];
    const float* w_in_b  = (const float*)d_in[3];
    const float* b_in_b  = (const float*)d_in[4];
    const float* w_out_a = (const float*)d_in[5];
    const float* b_out_a = (const float*)d_in[6];
    const float* w_out_b = (const float*)d_in[7];
    const float* b_out_b = (const float*)d_in[8];
    const float* cb_a    = (const float*)d_in[9];
    const float* cb_b    = (const float*)d_in[10];
    float* out = (float*)d_out;
    double* ws = (double*)d_ws;

    const bool pre = (ws_size >= WS_NEED_BYTES);
    if (pre) {
        vq_prep<<<96, 256, 0, stream>>>(w_in_a, w_in_b, cb_a, cb_b, ws);
        vq_main<true><<<512, 256, 0, stream>>>(z, w_in_a, b_in_a, w_in_b, b_in_b,
                                               w_out_a, b_out_a, w_out_b, b_out_b,
                                               cb_a, cb_b, out,
                                               ws + WSI_WIN, ws + WSI_CBNA, ws + WSI_CBNB,
                                               ws + WSI_PART_PRE);
        vq_finalize<<<1, 64, 0, stream>>>(ws + WSI_PART_PRE, out);
    } else {
        vq_main<false><<<512, 256, 0, stream>>>(z, w_in_a, b_in_a, w_in_b, b_in_b,
                                                w_out_a, b_out_a, w_out_b, b_out_b,
                                                cb_a, cb_b, out,
                                                ws, ws, ws, ws);
        vq_finalize<<<1, 64, 0, stream>>>(ws, out);
    }
}